// Round 1
// baseline (623.774 us; speedup 1.0000x reference)
//
#include <hip/hip_runtime.h>

// Problem constants (fixed by setup_inputs in the reference)
#define B_  8
#define N_  3072
#define C_  256
#define H_  128
#define W_  96
#define HW_ (H_ * W_)
#define EPSF 1e-6f

// Gaussian 3x3, sigma=2: w = exp(-(dx^2+dy^2)/8) / sum
// center, edge, corner (computed in double, rounded to float):
#define KW0 0.13080118f
#define KW1 0.11543166f
#define KW2 0.10186807f

// Pass 1: scatter-add each token's 256 features + count into NCHW acc (d_out)
// grid = B*N blocks, 256 threads (one per channel)
__global__ void scatter_k(const float* __restrict__ x, const float* __restrict__ loc,
                          float* __restrict__ acc, float* __restrict__ cnt) {
    const int token = blockIdx.x;
    const int c = threadIdx.x;
    const int b = token / N_;

    const float lx = fminf(fmaxf(loc[2 * token + 0], -1.0f), 1.0f);
    const float ly = fminf(fmaxf(loc[2 * token + 1], -1.0f), 1.0f);
    const float px = 0.5f * (lx + 1.0f) * (float)W_ - 0.5f;
    const float py = 0.5f * (ly + 1.0f) * (float)H_ - 0.5f;
    int ix = (int)rintf(px); ix = min(max(ix, 0), W_ - 1);   // rintf = round-half-even, matches jnp.round
    int iy = (int)rintf(py); iy = min(max(iy, 0), H_ - 1);
    const int pix = iy * W_ + ix;

    const float v = x[(size_t)token * C_ + c];
    atomicAdd(&acc[((size_t)(b * C_ + c)) * HW_ + pix], v);
    if (c == 0) atomicAdd(&cnt[b * HW_ + pix], 1.0f);
}

// Pass 2: normalize nonempty cells in place: acc /= (count + eps). Empty cells stay 0.
__global__ void norm_k(float* __restrict__ acc, const float* __restrict__ cnt) {
    const int i = blockIdx.x * 256 + threadIdx.x;   // i in [0, B*C*HW)
    const int pix = i % HW_;
    const int b = i / (C_ * HW_);
    const float ct = cnt[b * HW_ + pix];
    if (ct > 0.0f) {
        acc[i] = acc[i] / (ct + EPSF);
    }
}

// Pass 3: fill empty cells from 3x3 gaussian over nonempty neighbors.
// Race-free in place: reads are gated by cnt>0 (never reads an empty cell's value),
// writes touch only empty cells.
__global__ void fill_k(float* __restrict__ acc, const float* __restrict__ cnt) {
    const int i = blockIdx.x * 256 + threadIdx.x;
    const int xx = i % W_;
    const int y  = (i / W_) % H_;
    const int c  = (i / HW_) % C_;
    const int b  = i / (C_ * HW_);

    const float* cb = cnt + b * HW_;
    if (cb[y * W_ + xx] > 0.0f) return;   // nonempty: output is the normalized mean, already stored

    const float* ab = acc + ((size_t)(b * C_ + c)) * HW_;
    float fsum = 0.0f, msum = 0.0f;
    #pragma unroll
    for (int dy = -1; dy <= 1; ++dy) {
        const int yy = y + dy;
        if (yy < 0 || yy >= H_) continue;   // zero padding
        #pragma unroll
        for (int dx = -1; dx <= 1; ++dx) {
            const int xn = xx + dx;
            if (xn < 0 || xn >= W_) continue;
            const float cn = cb[yy * W_ + xn];
            if (cn > 0.0f) {
                const float w = (dy == 0) ? ((dx == 0) ? KW0 : KW1)
                                          : ((dx == 0) ? KW1 : KW2);
                fsum += w * ab[yy * W_ + xn];
                msum += w;
            }
        }
    }
    acc[i] = (msum > 0.0f) ? (fsum / (msum + EPSF)) : 0.0f;
}

extern "C" void kernel_launch(void* const* d_in, const int* in_sizes, int n_in,
                              void* d_out, int out_size, void* d_ws, size_t ws_size,
                              hipStream_t stream) {
    const float* x   = (const float*)d_in[0];   // (B, N, C) f32
    const float* loc = (const float*)d_in[1];   // (B, N, 2) f32
    float* acc = (float*)d_out;                 // (B, C, H, W) f32 — accumulator then final output
    float* cnt = (float*)d_ws;                  // (B, H, W) f32 counts

    hipMemsetAsync(d_out, 0, (size_t)out_size * sizeof(float), stream);
    hipMemsetAsync(d_ws, 0, (size_t)B_ * HW_ * sizeof(float), stream);

    scatter_k<<<B_ * N_, C_, 0, stream>>>(x, loc, acc, cnt);

    const int total = B_ * C_ * HW_;            // == out_size
    norm_k<<<total / 256, 256, 0, stream>>>(acc, cnt);
    fill_k<<<total / 256, 256, 0, stream>>>(acc, cnt);
}

// Round 2
// 300.146 us; speedup vs baseline: 2.0782x; 2.0782x over previous
//
#include <hip/hip_runtime.h>

// Problem constants (fixed by setup_inputs in the reference)
#define B_  8
#define N_  3072
#define C_  256
#define H_  128
#define W_  96
#define HW_ (H_ * W_)
#define NC_ (B_ * HW_)          // 98304 cells
#define NT_ (B_ * N_)           // 24576 tokens
#define EPSF 1e-6f

// Gaussian 3x3, sigma=2 (normalized): center, edge, corner
#define KW0 0.13080118f
#define KW1 0.11543166f
#define KW2 0.10186807f

// ws layout (u32 units):
//   Astart : [0, NC_+1)                exclusive scan of counts (+ total at end)
//   Acur   : [NC_+1, NC_+1+NC_)        counts, then cursors
//   Bsum   : [2*NC_+1, +384)
//   Boff   : [2*NC_+1+384, +384)
//   toks   : [2*NC_+1+768, +NT_)       packed (x<<20)|token, grouped by cell
#define OFF_ASTART 0
#define OFF_ACUR   (NC_ + 1)
#define OFF_BSUM   (2 * NC_ + 1)
#define OFF_BOFF   (2 * NC_ + 1 + 384)
#define OFF_TOKS   (2 * NC_ + 1 + 768)
// total = 2*NC_+1+768+NT_ = 221953 u32 ~ 888 KB

__device__ __forceinline__ void token_cell(const float* __restrict__ loc, int token,
                                           int& b, int& ix, int& iy) {
    b = token / N_;
    const float lx = fminf(fmaxf(loc[2 * token + 0], -1.0f), 1.0f);
    const float ly = fminf(fmaxf(loc[2 * token + 1], -1.0f), 1.0f);
    const float px = 0.5f * (lx + 1.0f) * (float)W_ - 0.5f;
    const float py = 0.5f * (ly + 1.0f) * (float)H_ - 0.5f;
    ix = (int)rintf(px); ix = min(max(ix, 0), W_ - 1);   // rintf = round-half-even = jnp.round
    iy = (int)rintf(py); iy = min(max(iy, 0), H_ - 1);
}

// Pass 1: histogram tokens into cells
__global__ void count_k(const float* __restrict__ loc, unsigned* __restrict__ cnts) {
    const int token = blockIdx.x * 256 + threadIdx.x;   // NT_ threads
    int b, ix, iy;
    token_cell(loc, token, b, ix, iy);
    atomicAdd(&cnts[b * HW_ + iy * W_ + ix], 1u);
}

// Pass 2a: per-block (256-cell) sums
__global__ void scanA(const unsigned* __restrict__ cnts, unsigned* __restrict__ Bsum) {
    const int i = blockIdx.x * 256 + threadIdx.x;
    int c = (int)cnts[i];
    #pragma unroll
    for (int off = 32; off > 0; off >>= 1) c += __shfl_down(c, off, 64);
    __shared__ int s[4];
    if ((threadIdx.x & 63) == 0) s[threadIdx.x >> 6] = c;
    __syncthreads();
    if (threadIdx.x == 0) Bsum[blockIdx.x] = (unsigned)(s[0] + s[1] + s[2] + s[3]);
}

// Pass 2b: exclusive scan of the 384 block sums (single block)
__global__ void scanB(const unsigned* __restrict__ Bsum, unsigned* __restrict__ Boff) {
    __shared__ unsigned s[512];
    const int t = threadIdx.x;
    const unsigned v = (t < 384) ? Bsum[t] : 0u;
    s[t] = v;
    __syncthreads();
    #pragma unroll
    for (int off = 1; off < 512; off <<= 1) {
        const unsigned a = (t >= off) ? s[t - off] : 0u;
        __syncthreads();
        s[t] += a;
        __syncthreads();
    }
    if (t < 384) Boff[t] = s[t] - v;   // exclusive
}

// Pass 2c: per-block exclusive scan + block offset -> Astart (and cursor copy)
__global__ void scanC(const unsigned* __restrict__ Boff,
                      unsigned* __restrict__ Astart, unsigned* __restrict__ Acur) {
    __shared__ unsigned s[256];
    const int t = threadIdx.x;
    const int i = blockIdx.x * 256 + t;
    const unsigned v = Acur[i];        // counts currently live in Acur
    s[t] = v;
    __syncthreads();
    #pragma unroll
    for (int off = 1; off < 256; off <<= 1) {
        const unsigned a = (t >= off) ? s[t - off] : 0u;
        __syncthreads();
        s[t] += a;
        __syncthreads();
    }
    const unsigned excl = s[t] - v + Boff[blockIdx.x];
    Astart[i] = excl;
    Acur[i]   = excl;                  // cursor starts at bin start
    if (i == 0) Astart[NC_] = NT_;     // total (every token maps to exactly one cell)
}

// Pass 3: scatter token ids (packed with x) into bins
__global__ void fill_bins(const float* __restrict__ loc,
                          unsigned* __restrict__ Acur, unsigned* __restrict__ toks) {
    const int token = blockIdx.x * 256 + threadIdx.x;
    int b, ix, iy;
    token_cell(loc, token, b, ix, iy);
    const unsigned pos = atomicAdd(&Acur[b * HW_ + iy * W_ + ix], 1u);
    toks[pos] = ((unsigned)ix << 20) | (unsigned)token;
}

// Pass 4: per-(b,y) row gather + normalize + transposed coalesced NCHW write.
// Reads each token's 256-float row exactly once (coalesced 1 KB), accumulates
// per-cell while walking the cell-grouped token list.
__global__ __launch_bounds__(256) void gather_norm(const float* __restrict__ xf,
        const unsigned* __restrict__ Astart, const unsigned* __restrict__ toks,
        float* __restrict__ out) {
    const int blk = blockIdx.x;          // 0..1023 = (b,y)
    const int b = blk >> 7;
    const int y = blk & 127;
    const int tid = threadIdx.x;         // channel
    const int rowbase = b * HW_ + y * W_;
    __shared__ float tile[32][257];
    __shared__ unsigned rs[33];

    for (int xt = 0; xt < 3; ++xt) {     // 3 tiles of 32 x-positions
        const int xbase = xt * 32;
        if (tid < 33) rs[tid] = Astart[rowbase + xbase + tid];
        #pragma unroll
        for (int xi = 0; xi < 32; ++xi) tile[xi][tid] = 0.0f;
        __syncthreads();

        const unsigned r0 = rs[0], r1 = rs[32];
        int cur_x = -1;
        float acc = 0.0f;
        for (unsigned p = r0; p < r1; p += 4) {
            unsigned vv[4]; float ff[4];
            #pragma unroll
            for (int j = 0; j < 4; ++j)
                if (p + j < r1) vv[j] = toks[p + j];
            #pragma unroll
            for (int j = 0; j < 4; ++j)
                if (p + j < r1) ff[j] = xf[(size_t)(vv[j] & 0xFFFFFu) * C_ + tid];
            #pragma unroll
            for (int j = 0; j < 4; ++j) {
                if (p + j >= r1) break;
                const int x = (int)(vv[j] >> 20);
                if (x != cur_x) {
                    if (cur_x >= 0) tile[cur_x & 31][tid] = acc;
                    acc = 0.0f;
                    cur_x = x;
                }
                acc += ff[j];
            }
        }
        if (cur_x >= 0) tile[cur_x & 31][tid] = acc;
        __syncthreads();

        // write out: lanes 0..31 along x (128B contiguous), 8 channels per pass
        const int x_off = tid & 31, cg = tid >> 5;
        const unsigned k = rs[x_off + 1] - rs[x_off];
        const float rcp = 1.0f / ((float)k + EPSF);
        const size_t obase = ((size_t)(b * C_)) * HW_ + y * W_ + xbase + x_off;
        #pragma unroll
        for (int cp = 0; cp < 32; ++cp) {
            const int c = cp * 8 + cg;
            out[obase + (size_t)c * HW_] = tile[x_off][c] * rcp;
        }
        __syncthreads();
    }
}

// Pass 5: fill empty cells from 3x3 gaussian over nonempty neighbors (in place,
// race-free: reads gated by count>0, writes touch only empty cells).
__global__ void fill_k(float* __restrict__ acc, const unsigned* __restrict__ Astart) {
    const int i = blockIdx.x * 256 + threadIdx.x;
    const int xx = i % W_;
    const int y  = (i / W_) % H_;
    const int b  = i / (C_ * HW_);

    const unsigned* rowA = Astart + b * HW_;
    if (rowA[y * W_ + xx + 1] > rowA[y * W_ + xx]) return;   // nonempty

    const float* ab = acc + (size_t)(i / HW_) * HW_;         // this (b,c) plane
    float fsum = 0.0f, msum = 0.0f;
    #pragma unroll
    for (int dy = -1; dy <= 1; ++dy) {
        const int yy = y + dy;
        if (yy < 0 || yy >= H_) continue;
        #pragma unroll
        for (int dx = -1; dx <= 1; ++dx) {
            const int xn = xx + dx;
            if (xn < 0 || xn >= W_) continue;
            const int nc = yy * W_ + xn;
            if (rowA[nc + 1] > rowA[nc]) {
                const float w = (dy == 0) ? ((dx == 0) ? KW0 : KW1)
                                          : ((dx == 0) ? KW1 : KW2);
                fsum += w * ab[nc];
                msum += w;
            }
        }
    }
    acc[i] = (msum > 0.0f) ? (fsum / (msum + EPSF)) : 0.0f;
}

extern "C" void kernel_launch(void* const* d_in, const int* in_sizes, int n_in,
                              void* d_out, int out_size, void* d_ws, size_t ws_size,
                              hipStream_t stream) {
    const float* x   = (const float*)d_in[0];   // (B, N, C) f32
    const float* loc = (const float*)d_in[1];   // (B, N, 2) f32
    float* out = (float*)d_out;                 // (B, C, H, W) f32

    unsigned* W32 = (unsigned*)d_ws;
    unsigned* Astart = W32 + OFF_ASTART;
    unsigned* Acur   = W32 + OFF_ACUR;
    unsigned* Bsum   = W32 + OFF_BSUM;
    unsigned* Boff   = W32 + OFF_BOFF;
    unsigned* toks   = W32 + OFF_TOKS;

    // zero the counts region (Acur)
    hipMemsetAsync(Acur, 0, (size_t)NC_ * sizeof(unsigned), stream);

    count_k  <<<NT_ / 256, 256, 0, stream>>>(loc, Acur);
    scanA    <<<NC_ / 256, 256, 0, stream>>>(Acur, Bsum);
    scanB    <<<1, 512, 0, stream>>>(Bsum, Boff);
    scanC    <<<NC_ / 256, 256, 0, stream>>>(Boff, Astart, Acur);
    fill_bins<<<NT_ / 256, 256, 0, stream>>>(loc, Acur, toks);

    gather_norm<<<B_ * H_, 256, 0, stream>>>(x, Astart, toks, out);

    fill_k<<<(B_ * C_ * HW_) / 256, 256, 0, stream>>>(out, Astart);
}

// Round 4
// 132.826 us; speedup vs baseline: 4.6962x; 2.2597x over previous
//
#include <hip/hip_runtime.h>

// Problem constants (fixed by setup_inputs in the reference)
#define B_  8
#define N_  3072
#define C_  256
#define H_  128
#define W_  96
#define HW_ (H_ * W_)
#define NC_ (B_ * HW_)          // 98304 cells
#define NT_ (B_ * N_)           // 24576 tokens
#define EPSF 1e-6f

// Gaussian 3x3, sigma=2 (normalized): center, edge, corner
#define KW0 0.13080118f
#define KW1 0.11543166f
#define KW2 0.10186807f

// ws layout (u32 units)
#define OFF_ASTART 0
#define OFF_ACUR   (NC_ + 1)
#define OFF_BSUM   (2 * NC_ + 1)
#define OFF_BOFF   (2 * NC_ + 1 + 384)
#define OFF_TOKS   (2 * NC_ + 1 + 768)
#define OFF_EMASK  (OFF_TOKS + NT_ + 1)   // +1 pad -> even u32 offset (u64-aligned)
// total = OFF_EMASK + NC_/32 = 225026 u32 ~ 900 KB

__device__ __forceinline__ void token_cell(const float* __restrict__ loc, int token,
                                           int& b, int& ix, int& iy) {
    b = token / N_;
    const float lx = fminf(fmaxf(loc[2 * token + 0], -1.0f), 1.0f);
    const float ly = fminf(fmaxf(loc[2 * token + 1], -1.0f), 1.0f);
    const float px = 0.5f * (lx + 1.0f) * (float)W_ - 0.5f;
    const float py = 0.5f * (ly + 1.0f) * (float)H_ - 0.5f;
    ix = (int)rintf(px); ix = min(max(ix, 0), W_ - 1);   // rintf = round-half-even = jnp.round
    iy = (int)rintf(py); iy = min(max(iy, 0), H_ - 1);
}

// Pass 1: histogram tokens into cells
__global__ void count_k(const float* __restrict__ loc, unsigned* __restrict__ cnts) {
    const int token = blockIdx.x * 256 + threadIdx.x;   // NT_ threads
    int b, ix, iy;
    token_cell(loc, token, b, ix, iy);
    atomicAdd(&cnts[b * HW_ + iy * W_ + ix], 1u);
}

// Pass 2a: per-block (256-cell) sums
__global__ void scanA(const unsigned* __restrict__ cnts, unsigned* __restrict__ Bsum) {
    const int i = blockIdx.x * 256 + threadIdx.x;
    int c = (int)cnts[i];
    #pragma unroll
    for (int off = 32; off > 0; off >>= 1) c += __shfl_down(c, off, 64);
    __shared__ int s[4];
    if ((threadIdx.x & 63) == 0) s[threadIdx.x >> 6] = c;
    __syncthreads();
    if (threadIdx.x == 0) Bsum[blockIdx.x] = (unsigned)(s[0] + s[1] + s[2] + s[3]);
}

// Pass 2b: exclusive scan of the 384 block sums (single block)
__global__ void scanB(const unsigned* __restrict__ Bsum, unsigned* __restrict__ Boff) {
    __shared__ unsigned s[512];
    const int t = threadIdx.x;
    const unsigned v = (t < 384) ? Bsum[t] : 0u;
    s[t] = v;
    __syncthreads();
    #pragma unroll
    for (int off = 1; off < 512; off <<= 1) {
        const unsigned a = (t >= off) ? s[t - off] : 0u;
        __syncthreads();
        s[t] += a;
        __syncthreads();
    }
    if (t < 384) Boff[t] = s[t] - v;   // exclusive
}

// Pass 2c: per-block exclusive scan + block offset -> Astart (and cursor copy)
__global__ void scanC(const unsigned* __restrict__ Boff,
                      unsigned* __restrict__ Astart, unsigned* __restrict__ Acur) {
    __shared__ unsigned s[256];
    const int t = threadIdx.x;
    const int i = blockIdx.x * 256 + t;
    const unsigned v = Acur[i];        // counts currently live in Acur
    s[t] = v;
    __syncthreads();
    #pragma unroll
    for (int off = 1; off < 256; off <<= 1) {
        const unsigned a = (t >= off) ? s[t - off] : 0u;
        __syncthreads();
        s[t] += a;
        __syncthreads();
    }
    const unsigned excl = s[t] - v + Boff[blockIdx.x];
    Astart[i] = excl;
    Acur[i]   = excl;                  // cursor starts at bin start
    if (i == 0) Astart[NC_] = NT_;     // total
}

// Pass 3: scatter token ids (packed with x) into bins
__global__ void fill_bins(const float* __restrict__ loc,
                          unsigned* __restrict__ Acur, unsigned* __restrict__ toks) {
    const int token = blockIdx.x * 256 + threadIdx.x;
    int b, ix, iy;
    token_cell(loc, token, b, ix, iy);
    const unsigned pos = atomicAdd(&Acur[b * HW_ + iy * W_ + ix], 1u);
    toks[pos] = ((unsigned)ix << 20) | (unsigned)token;
}

// Pass 3b: pack per-cell nonempty bits (1 = nonempty), 64 cells/word via ballot
__global__ void mask_k(const unsigned* __restrict__ Astart,
                       unsigned long long* __restrict__ emask64) {
    const int i = blockIdx.x * 256 + threadIdx.x;    // NC_ threads exactly
    const bool nonempty = Astart[i + 1] > Astart[i];
    const unsigned long long m = __ballot(nonempty);
    if ((threadIdx.x & 63) == 0) emask64[i >> 6] = m;
}

// Pass 4: per-(b,y) row gather + normalize + transposed coalesced NCHW write.
__global__ __launch_bounds__(256) void gather_norm(const float* __restrict__ xf,
        const unsigned* __restrict__ Astart, const unsigned* __restrict__ toks,
        float* __restrict__ out) {
    const int blk = blockIdx.x;          // 0..1023 = (b,y)
    const int b = blk >> 7;
    const int y = blk & 127;
    const int tid = threadIdx.x;         // channel
    const int rowbase = b * HW_ + y * W_;
    __shared__ float tile[32][257];
    __shared__ unsigned rs[33];

    for (int xt = 0; xt < 3; ++xt) {     // 3 tiles of 32 x-positions
        const int xbase = xt * 32;
        if (tid < 33) rs[tid] = Astart[rowbase + xbase + tid];
        #pragma unroll
        for (int xi = 0; xi < 32; ++xi) tile[xi][tid] = 0.0f;
        __syncthreads();

        const unsigned r0 = rs[0], r1 = rs[32];
        int cur_x = -1;
        float acc = 0.0f;
        for (unsigned p = r0; p < r1; p += 4) {
            unsigned vv[4]; float ff[4];
            #pragma unroll
            for (int j = 0; j < 4; ++j)
                if (p + j < r1) vv[j] = toks[p + j];
            #pragma unroll
            for (int j = 0; j < 4; ++j)
                if (p + j < r1) ff[j] = xf[(size_t)(vv[j] & 0xFFFFFu) * C_ + tid];
            #pragma unroll
            for (int j = 0; j < 4; ++j) {
                if (p + j >= r1) break;
                const int x = (int)(vv[j] >> 20);
                if (x != cur_x) {
                    if (cur_x >= 0) tile[cur_x & 31][tid] = acc;
                    acc = 0.0f;
                    cur_x = x;
                }
                acc += ff[j];
            }
        }
        if (cur_x >= 0) tile[cur_x & 31][tid] = acc;
        __syncthreads();

        const int x_off = tid & 31, cg = tid >> 5;
        const unsigned k = rs[x_off + 1] - rs[x_off];
        const float rcp = 1.0f / ((float)k + EPSF);
        const size_t obase = ((size_t)(b * C_)) * HW_ + y * W_ + xbase + x_off;
        #pragma unroll
        for (int cp = 0; cp < 32; ++cp) {
            const int c = cp * 8 + cg;
            out[obase + (size_t)c * HW_] = tile[x_off][c] * rcp;
        }
        __syncthreads();
    }
}

// Pass 5: LDS-staged hole fill. Block = one 32-row stripe of one (b,c) plane.
// Stages stripe+halo values and the per-cell nonempty bitmask in LDS; writes
// only empty cells. Race-free: only nonempty (never-written) values are read.
__global__ __launch_bounds__(256) void fill_plane(float* __restrict__ out,
        const unsigned* __restrict__ emask) {
    const int blk = blockIdx.x;          // (b*C_+c)*4 + stripe
    const int stripe = blk & 3;
    const int plane = blk >> 2;          // b*C_ + c
    const int b = plane >> 8;
    const int y0 = stripe * 32;
    const int yh0 = (y0 == 0) ? 0 : (y0 - 1);
    const int yhi = (y0 + 33 > H_) ? H_ : (y0 + 33);
    const int nrows = yhi - yh0;         // 33 or 34

    __shared__ float sv[34 * 96];
    __shared__ unsigned sm[102];

    float* pl = out + (size_t)plane * HW_;
    const int t = threadIdx.x;

    // stage mask words (3 u32 per row; base word index is 32-aligned since
    // b*HW_ and yh0*96 are multiples of 32) and plane rows [yh0, yhi)
    const int nwords = nrows * 3;
    if (t < nwords) sm[t] = emask[((b * HW_ + yh0 * W_) >> 5) + t];
    const int nvec = nrows * (W_ / 4);
    const float4* src = (const float4*)(pl + yh0 * W_);
    float4* dst = (float4*)sv;
    #pragma unroll
    for (int k = 0; k < 4; ++k) {
        const int idx = t + k * 256;
        if (idx < nvec) dst[idx] = src[idx];
    }
    __syncthreads();

    // each thread: 12 cells of the 32x96 stripe
    #pragma unroll
    for (int k = 0; k < 12; ++k) {
        const int cell = t + k * 256;
        const int yrel = cell / 96;
        const int x = cell - yrel * 96;
        const int y = y0 + yrel;
        const int lrow = y - yh0;
        if ((sm[lrow * 3 + (x >> 5)] >> (x & 31)) & 1u) continue;   // nonempty
        float fsum = 0.0f, msum = 0.0f;
        #pragma unroll
        for (int dy = -1; dy <= 1; ++dy) {
            const int yy = y + dy;
            if (yy < 0 || yy >= H_) continue;
            const int lr = yy - yh0;
            #pragma unroll
            for (int dx = -1; dx <= 1; ++dx) {
                const int xn = x + dx;
                if (xn < 0 || xn >= W_) continue;
                if ((sm[lr * 3 + (xn >> 5)] >> (xn & 31)) & 1u) {
                    const float w = (dy == 0) ? ((dx == 0) ? KW0 : KW1)
                                              : ((dx == 0) ? KW1 : KW2);
                    fsum += w * sv[lr * 96 + xn];
                    msum += w;
                }
            }
        }
        pl[y * W_ + x] = (msum > 0.0f) ? fsum / (msum + EPSF) : 0.0f;
    }
}

extern "C" void kernel_launch(void* const* d_in, const int* in_sizes, int n_in,
                              void* d_out, int out_size, void* d_ws, size_t ws_size,
                              hipStream_t stream) {
    const float* x   = (const float*)d_in[0];   // (B, N, C) f32
    const float* loc = (const float*)d_in[1];   // (B, N, 2) f32
    float* out = (float*)d_out;                 // (B, C, H, W) f32

    unsigned* W32 = (unsigned*)d_ws;
    unsigned* Astart = W32 + OFF_ASTART;
    unsigned* Acur   = W32 + OFF_ACUR;
    unsigned* Bsum   = W32 + OFF_BSUM;
    unsigned* Boff   = W32 + OFF_BOFF;
    unsigned* toks   = W32 + OFF_TOKS;
    unsigned* emask  = W32 + OFF_EMASK;

    hipMemsetAsync(Acur, 0, (size_t)NC_ * sizeof(unsigned), stream);

    count_k  <<<NT_ / 256, 256, 0, stream>>>(loc, Acur);
    scanA    <<<NC_ / 256, 256, 0, stream>>>(Acur, Bsum);
    scanB    <<<1, 512, 0, stream>>>(Bsum, Boff);
    scanC    <<<NC_ / 256, 256, 0, stream>>>(Boff, Astart, Acur);
    fill_bins<<<NT_ / 256, 256, 0, stream>>>(loc, Acur, toks);
    mask_k   <<<NC_ / 256, 256, 0, stream>>>(Astart, (unsigned long long*)emask);

    gather_norm<<<B_ * H_, 256, 0, stream>>>(x, Astart, toks, out);

    fill_plane<<<B_ * C_ * 4, 256, 0, stream>>>(out, emask);
}